// Round 13
// baseline (110.006 us; speedup 1.0000x reference)
//
#include <hip/hip_runtime.h>
#include <cfloat>

#define NB 4096           // nodes per batch
#define FD 64             // feature dim
#define QPB 8             // queries per block (2 per wave)
#define LRELU_ALPHA 0.2f
#define CCAP 96           // per-query candidate cap (E[cands] ~ 30 w/ slack)

__device__ __forceinline__ float rfl(float v) {
    return __int_as_float(__builtin_amdgcn_readfirstlane(__float_as_int(v)));
}

// prep: blocks 0..511: Wh = x@W, f1 = Wh@a[:64], f2 = Wh@a[64:]
//       blocks 512..543: pq[i] = (x,y,z, 0.5*|p|^2 fast)
__global__ __launch_bounds__(256) void prep_kernel(
    const float* __restrict__ x, const float* __restrict__ pos,
    const float* __restrict__ W, const float* __restrict__ a,
    float* __restrict__ Wh, float* __restrict__ f1, float* __restrict__ f2,
    float4* __restrict__ pq)
{
    const int tid = threadIdx.x;
    if (blockIdx.x >= 512) {
        const int i = (blockIdx.x - 512) * 256 + tid;   // 0..8191
        const float px = pos[i * 3 + 0];
        const float py = pos[i * 3 + 1];
        const float pz = pos[i * 3 + 2];
        pq[i] = make_float4(px, py, pz, 0.5f * fmaf(pz, pz, fmaf(py, py, px * px)));
        return;
    }
    __shared__ float sW[FD * FD];
    #pragma unroll
    for (int t = 0; t < 16; ++t) sW[tid + t * 256] = W[tid + t * 256];
    __syncthreads();
    const int lane = tid & 63, wave = tid >> 6;
    const float a1v = a[lane], a2v = a[FD + lane];
    const int rbase = blockIdx.x * 16 + wave * 4;
    #pragma unroll
    for (int j = 0; j < 4; j += 2) {                 // 2 rows in flight (ILP)
        const int r0 = rbase + j, r1 = rbase + j + 1;
        const float xv0 = x[((size_t)r0 << 6) + lane];
        const float xv1 = x[((size_t)r1 << 6) + lane];
        float acc0 = 0.f, acc1 = 0.f;
        #pragma unroll
        for (int i = 0; i < FD; ++i) {
            const float wv = sW[i * FD + lane];
            acc0 = fmaf(__shfl(xv0, i, 64), wv, acc0);
            acc1 = fmaf(__shfl(xv1, i, 64), wv, acc1);
        }
        Wh[((size_t)r0 << 6) + lane] = acc0;
        Wh[((size_t)r1 << 6) + lane] = acc1;
        float s10 = acc0 * a1v, s20 = acc0 * a2v;
        float s11 = acc1 * a1v, s21 = acc1 * a2v;
        #pragma unroll
        for (int off = 32; off > 0; off >>= 1) {
            s10 += __shfl_down(s10, off, 64);
            s20 += __shfl_down(s20, off, 64);
            s11 += __shfl_down(s11, off, 64);
            s21 += __shfl_down(s21, off, 64);
        }
        if (lane == 0) { f1[r0] = s10; f2[r0] = s20; f1[r1] = s11; f2[r1] = s21; }
    }
}

// 8 queries/block (R12 lesson: the sweep is L2-stream-traffic bound — one
// pq load must feed more screens). Query xyz held in SGPRs (readfirstlane;
// block-uniform) so 8 running minima keep VGPR < 64 (R10 lesson). Screen
// metric e = 0.5|p|^2 - q.p (order == d2 order per query). Pass 1: per-thread
// e-min + bitonic of 64 disjoint-group minima (each wave sorts 2 queries) ->
// provable bound T (sorted[k] >= global (k+1)-th smallest). Pass 2: append-
// index-only, slack >> fast-vs-rn gap -> candidates ⊇ exact top-(k+1).
// Select: exact rn-op-order d2 (raw pos) -> u64 (d2,idx) rank = bit-identical
// jax.lax.top_k stable order; rank 0 dropped (= ref col 0). Phase B:
// wave-private softmax + 20 coalesced Wh-row fmas, 2 queries per wave.
__global__ __launch_bounds__(256, 8) void gat_fused(
    const float* __restrict__ pos, const float4* __restrict__ pq,
    const float* __restrict__ Wh,
    const float* __restrict__ f1, const float* __restrict__ f2,
    const float* __restrict__ Wp, const float* __restrict__ bp,
    const int* __restrict__ kptr, float* __restrict__ out)
{
    __shared__ union Pool {
        float tmin[QPB * 256];                         // phase A1 (8 KB)
        struct {
            unsigned long long pkbuf[QPB][CCAP];       // select (6 KB)
            int cidx[QPB][CCAP];                       // pass 2 (3 KB)
        } s;
    } pool;
    __shared__ float4 sq[QPB];                         // qx,qy,qz,|q|^2 (rn)
    __shared__ float sT[QPB];
    __shared__ unsigned int cnt[QPB];
    __shared__ int idx21[QPB][24];

    const int tid = threadIdx.x;
    const int lane = tid & 63, wave = tid >> 6;
    const int qbase = blockIdx.x * QPB;                // row of query 0
    const int b = qbase >> 12;                         // same batch (4096%8==0)
    const float* posb = pos + (size_t)b * NB * 3;
    const float4* pq4 = pq + ((size_t)b << 12);
    const int k = *kptr;                               // 20

    if (tid < QPB) {
        const int nq = (qbase + tid) & (NB - 1);
        const float ax = posb[nq * 3 + 0], ay = posb[nq * 3 + 1], az = posb[nq * 3 + 2];
        const float sr = __fadd_rn(__fadd_rn(__fmul_rn(ax, ax), __fmul_rn(ay, ay)),
                                   __fmul_rn(az, az));
        sq[tid] = make_float4(ax, ay, az, sr);
        cnt[tid] = 0;
    }
    // safety net: in-bounds defaults (provably overwritten)
    if (lane < 24) {
        idx21[2 * wave][lane]     = (qbase + 2 * wave) & (NB - 1);
        idx21[2 * wave + 1][lane] = (qbase + 2 * wave + 1) & (NB - 1);
    }
    __syncthreads();                                   // B1

    // block-uniform query coords -> SGPRs (readfirstlane), freeing VGPRs
    float qx[QPB], qy[QPB], qz[QPB];
    #pragma unroll
    for (int i = 0; i < QPB; ++i) {
        const int nq = (qbase + i) & (NB - 1);
        qx[i] = rfl(posb[nq * 3 + 0]);
        qy[i] = rfl(posb[nq * 3 + 1]);
        qz[i] = rfl(posb[nq * 3 + 2]);
    }

    // pass 1: fast screen, dense float4 stream, 8 screens per load
    float mn[QPB];
    #pragma unroll
    for (int i = 0; i < QPB; ++i) mn[i] = FLT_MAX;
    #pragma unroll 4
    for (int t = 0; t < 16; ++t) {
        const float4 p = pq4[t * 256 + tid];
        #pragma unroll
        for (int i = 0; i < QPB; ++i) {
            const float d = p.w - fmaf(qx[i], p.x, fmaf(qy[i], p.y, qz[i] * p.z));
            mn[i] = fminf(mn[i], d);
        }
    }
    #pragma unroll
    for (int i = 0; i < QPB; ++i) pool.tmin[i * 256 + tid] = mn[i];
    __syncthreads();                                   // B2

    // each wave bitonic-sorts 2 queries' 64 disjoint-group minima
    #pragma unroll
    for (int qi = 0; qi < 2; ++qi) {
        const int q = 2 * wave + qi;
        float v = fminf(fminf(pool.tmin[q * 256 + lane],
                              pool.tmin[q * 256 + 64 + lane]),
                        fminf(pool.tmin[q * 256 + 128 + lane],
                              pool.tmin[q * 256 + 192 + lane]));
        #pragma unroll
        for (int kk2 = 2; kk2 <= 64; kk2 <<= 1) {
            #pragma unroll
            for (int j = kk2 >> 1; j > 0; j >>= 1) {
                const float o = __shfl_xor(v, j, 64);
                const bool keepMin = (((lane & j) == 0) == ((lane & kk2) == 0));
                v = keepMin ? fminf(v, o) : fmaxf(v, o);
            }
        }
        const float Tq = __shfl(v, k, 64);             // all lanes (R8 lesson)
        if (lane == 0) sT[q] = Tq;
    }
    __syncthreads();                                   // B3 (tmin dead -> s.*)

    // slack >> all fast-vs-rn rounding gaps (~1e-6)
    float Ts[QPB];
    #pragma unroll
    for (int i = 0; i < QPB; ++i)
        Ts[i] = sT[i] + 1e-2f + 1e-3f * fabsf(sT[i]);

    // pass 2: re-screen (same stream); append index only
    #pragma unroll 2
    for (int t = 0; t < 16; ++t) {
        const int m = t * 256 + tid;
        const float4 p = pq4[m];
        #pragma unroll
        for (int i = 0; i < QPB; ++i) {
            const float d = p.w - fmaf(qx[i], p.x, fmaf(qy[i], p.y, qz[i] * p.z));
            if (d <= Ts[i]) {
                const unsigned int pp = atomicAdd(&cnt[i], 1u);
                if (pp < CCAP) pool.s.cidx[i][pp] = m;
            }
        }
    }
    __syncthreads();                                   // B4 — last barrier

    // select + phase B: wave w handles queries 2w, 2w+1 sequentially
    #pragma unroll
    for (int qi = 0; qi < 2; ++qi) {
        const int q = 2 * wave + qi;
        const float4 qq = sq[q];                       // LDS broadcast read
        const int cn0 = (int)cnt[q];
        const int cn = cn0 < CCAP ? cn0 : CCAP;
        for (int e = lane; e < cn; e += 64) {
            const int m = pool.s.cidx[q][e];
            const float px = posb[m * 3 + 0];
            const float py = posb[m * 3 + 1];
            const float pz = posb[m * 3 + 2];
            const float sqm = __fadd_rn(__fadd_rn(__fmul_rn(px, px), __fmul_rn(py, py)),
                                        __fmul_rn(pz, pz));
            const float dot = __fadd_rn(__fadd_rn(__fmul_rn(qq.x, px), __fmul_rn(qq.y, py)),
                                        __fmul_rn(qq.z, pz));
            const float d2 = __fsub_rn(__fadd_rn(qq.w, sqm), __fmul_rn(2.0f, dot));
            const unsigned int u = __float_as_uint(d2);
            const unsigned int kk = u ^ ((unsigned int)((int)u >> 31) | 0x80000000u);
            pool.s.pkbuf[q][e] = ((unsigned long long)kk << 12) | (unsigned int)m;
        }
        for (int e = lane; e < cn; e += 64) {
            const unsigned long long xv = pool.s.pkbuf[q][e];
            int r = 0;
            for (int j = 0; j < cn; ++j) r += (pool.s.pkbuf[q][j] < xv);
            if (r <= k) idx21[q][r] = (int)(xv & 0xFFFu);
        }
        // wave-private LDS RAW: in-order per wave + compiler lgkmcnt

        const int row = qbase + q;
        const bool valid = (lane >= 1 && lane <= k);
        const int nbr = valid ? idx21[q][lane] : 0;
        const float f1v = f1[row];
        float e = -FLT_MAX;
        if (valid) {
            e = f1v + f2[(b << 12) + nbr];
            e = e > 0.f ? e : LRELU_ALPHA * e;
        }
        float mx = e;
        #pragma unroll
        for (int off = 32; off > 0; off >>= 1) mx = fmaxf(mx, __shfl_xor(mx, off, 64));
        const float ex = valid ? __expf(e - mx) : 0.f;
        float Z = ex;
        #pragma unroll
        for (int off = 32; off > 0; off >>= 1) Z += __shfl_xor(Z, off, 64);
        const float attn = ex / Z;                     // lane t holds attn_t

        const float* whb = Wh + (((size_t)b << 12) << 6);
        float h = 0.f;
        #pragma unroll 4
        for (int t = 1; t <= k; ++t) {
            const int nb_ = __shfl(nbr, t, 64);
            const float s = __shfl(attn, t, 64);
            h = fmaf(s, whb[((size_t)nb_ << 6) + lane], h);
        }

        const float pv = fmaf(qq.x, Wp[0 * FD + lane],
                         fmaf(qq.y, Wp[1 * FD + lane],
                         fmaf(qq.z, Wp[2 * FD + lane], bp[lane])));
        h += pv > 0.f ? pv : 0.f;
        out[((size_t)row << 6) + lane] = h > 0.f ? h : expm1f(h);
    }
}

extern "C" void kernel_launch(void* const* d_in, const int* in_sizes, int n_in,
                              void* d_out, int out_size, void* d_ws, size_t ws_size,
                              hipStream_t stream) {
    const float* x   = (const float*)d_in[0];
    const float* pos = (const float*)d_in[1];
    const float* W   = (const float*)d_in[2];
    const float* a   = (const float*)d_in[3];
    const float* Wp  = (const float*)d_in[4];
    const float* bp  = (const float*)d_in[5];
    const int*   kp  = (const int*)d_in[6];

    float* ws = (float*)d_ws;
    float*  Wh = ws;                        // 8192*64 = 524288
    float*  f1 = Wh + 524288;               // 8192
    float*  f2 = f1 + 8192;                 // 8192
    float4* pq = (float4*)(f2 + 8192);      // 8192 float4 (16B-aligned)
    float*  out = (float*)d_out;

    prep_kernel<<<544, 256, 0, stream>>>(x, pos, W, a, Wh, f1, f2, pq);
    gat_fused<<<(NB * 2) / QPB, 256, 0, stream>>>(pos, pq, Wh, f1, f2, Wp, bp, kp, out);
}

// Round 14
// 102.343 us; speedup vs baseline: 1.0749x; 1.0749x over previous
//
#include <hip/hip_runtime.h>
#include <cfloat>

#define NB 4096           // nodes per batch
#define FD 64             // feature dim
#define NT 512            // threads per gat block
#define EPT 8             // nodes per thread = NB / NT
#define QPB 8             // queries per block (one per wave)
#define LRELU_ALPHA 0.2f
#define CCAP 96           // per-query candidate cap (E[cands] ~ 30 w/ slack)

__device__ __forceinline__ float rfl(float v) {
    return __int_as_float(__builtin_amdgcn_readfirstlane(__float_as_int(v)));
}

// prep: blocks 0..511: Wh = x@W, f1 = Wh@a[:64], f2 = Wh@a[64:]
//       blocks 512..543: pq[i] = (x,y,z, 0.5*|p|^2 fast)
__global__ __launch_bounds__(256) void prep_kernel(
    const float* __restrict__ x, const float* __restrict__ pos,
    const float* __restrict__ W, const float* __restrict__ a,
    float* __restrict__ Wh, float* __restrict__ f1, float* __restrict__ f2,
    float4* __restrict__ pq)
{
    const int tid = threadIdx.x;
    if (blockIdx.x >= 512) {
        const int i = (blockIdx.x - 512) * 256 + tid;   // 0..8191
        const float px = pos[i * 3 + 0];
        const float py = pos[i * 3 + 1];
        const float pz = pos[i * 3 + 2];
        pq[i] = make_float4(px, py, pz, 0.5f * fmaf(pz, pz, fmaf(py, py, px * px)));
        return;
    }
    __shared__ float sW[FD * FD];
    #pragma unroll
    for (int t = 0; t < 16; ++t) sW[tid + t * 256] = W[tid + t * 256];
    __syncthreads();
    const int lane = tid & 63, wave = tid >> 6;
    const float a1v = a[lane], a2v = a[FD + lane];
    const int rbase = blockIdx.x * 16 + wave * 4;
    #pragma unroll
    for (int j = 0; j < 4; j += 2) {                 // 2 rows in flight (ILP)
        const int r0 = rbase + j, r1 = rbase + j + 1;
        const float xv0 = x[((size_t)r0 << 6) + lane];
        const float xv1 = x[((size_t)r1 << 6) + lane];
        float acc0 = 0.f, acc1 = 0.f;
        #pragma unroll
        for (int i = 0; i < FD; ++i) {
            const float wv = sW[i * FD + lane];
            acc0 = fmaf(__shfl(xv0, i, 64), wv, acc0);
            acc1 = fmaf(__shfl(xv1, i, 64), wv, acc1);
        }
        Wh[((size_t)r0 << 6) + lane] = acc0;
        Wh[((size_t)r1 << 6) + lane] = acc1;
        float s10 = acc0 * a1v, s20 = acc0 * a2v;
        float s11 = acc1 * a1v, s21 = acc1 * a2v;
        #pragma unroll
        for (int off = 32; off > 0; off >>= 1) {
            s10 += __shfl_down(s10, off, 64);
            s20 += __shfl_down(s20, off, 64);
            s11 += __shfl_down(s11, off, 64);
            s21 += __shfl_down(s21, off, 64);
        }
        if (lane == 0) { f1[r0] = s10; f2[r0] = s20; f1[r1] = s11; f2[r1] = s21; }
    }
}

// 512 threads, 8 queries/block, ONE query per wave. Grid 1024 x 8 waves =
// 32 waves/CU (vs R13's 16 — its regression cause). One pq load feeds 8
// screens -> per-CU L2 stream ~4x lower than QPB=4. Per-thread minima are
// pre-reduced in-register (shfl_xor over 8-lane clusters) to 64 disjoint
// supergroup minima per query (2 KB LDS); sorted[k] of those is a provable
// screen bound (21 <= 64 supergroups, each contributes one element <= it).
// Pass 2: append-index-only with slack >> fast-vs-rn gap -> candidates ⊇
// exact top-(k+1). Select: exact rn-op-order d2 (raw pos) -> u64 (d2,idx)
// rank = bit-identical jax.lax.top_k stable order; rank 0 dropped (= ref
// col 0). Phase B: wave-private softmax + 20 coalesced Wh-row fmas.
// Query coords in SGPRs (readfirstlane); launch_bounds(512,8) caps VGPR<=64.
__global__ __launch_bounds__(NT, 8) void gat_fused(
    const float* __restrict__ pos, const float4* __restrict__ pq,
    const float* __restrict__ Wh,
    const float* __restrict__ f1, const float* __restrict__ f2,
    const float* __restrict__ Wp, const float* __restrict__ bp,
    const int* __restrict__ kptr, float* __restrict__ out)
{
    __shared__ union Pool {
        float tmin[QPB][64];                           // phase A1 (2 KB)
        struct {
            unsigned long long pkbuf[QPB][CCAP];       // select (6 KB)
            int cidx[QPB][CCAP];                       // pass 2 (3 KB)
        } s;
    } pool;
    __shared__ float4 sq[QPB];                         // qx,qy,qz,|q|^2 (rn)
    __shared__ float sT[QPB];
    __shared__ unsigned int cnt[QPB];
    __shared__ int idx21[QPB][24];

    const int tid = threadIdx.x;
    const int lane = tid & 63, wave = tid >> 6;        // wave 0..7 = query id
    const int qbase = blockIdx.x * QPB;                // row of query 0
    const int b = qbase >> 12;                         // same batch (4096%8==0)
    const float* posb = pos + (size_t)b * NB * 3;
    const float4* pq4 = pq + ((size_t)b << 12);
    const int k = *kptr;                               // 20

    if (tid < QPB) {
        const int nq = (qbase + tid) & (NB - 1);
        const float ax = posb[nq * 3 + 0], ay = posb[nq * 3 + 1], az = posb[nq * 3 + 2];
        const float sr = __fadd_rn(__fadd_rn(__fmul_rn(ax, ax), __fmul_rn(ay, ay)),
                                   __fmul_rn(az, az));
        sq[tid] = make_float4(ax, ay, az, sr);
        cnt[tid] = 0;
    }
    // safety net: in-bounds defaults (provably overwritten)
    if (lane < 24) idx21[wave][lane] = (qbase + wave) & (NB - 1);
    __syncthreads();                                   // B1

    // block-uniform query coords -> SGPRs (readfirstlane)
    float qx[QPB], qy[QPB], qz[QPB];
    #pragma unroll
    for (int i = 0; i < QPB; ++i) {
        const int nq = (qbase + i) & (NB - 1);
        qx[i] = rfl(posb[nq * 3 + 0]);
        qy[i] = rfl(posb[nq * 3 + 1]);
        qz[i] = rfl(posb[nq * 3 + 2]);
    }

    // pass 1: fast screen (e = 0.5|p|^2 - q.p; order == d2 order per query)
    float mn[QPB];
    #pragma unroll
    for (int i = 0; i < QPB; ++i) mn[i] = FLT_MAX;
    #pragma unroll 4
    for (int t = 0; t < EPT; ++t) {
        const float4 p = pq4[t * NT + tid];
        #pragma unroll
        for (int i = 0; i < QPB; ++i) {
            const float d = p.w - fmaf(qx[i], p.x, fmaf(qy[i], p.y, qz[i] * p.z));
            mn[i] = fminf(mn[i], d);
        }
    }
    // in-register pre-reduce: 8-lane clusters -> 64 supergroup minima/query
    #pragma unroll
    for (int i = 0; i < QPB; ++i) {
        float v = mn[i];
        v = fminf(v, __shfl_xor(v, 1, 64));
        v = fminf(v, __shfl_xor(v, 2, 64));
        v = fminf(v, __shfl_xor(v, 4, 64));
        if ((lane & 7) == 0) pool.tmin[i][wave * 8 + (lane >> 3)] = v;
    }
    __syncthreads();                                   // B2

    // wave w bitonic-sorts query w's 64 supergroup minima; T = sorted[k]
    {
        float v = pool.tmin[wave][lane];
        #pragma unroll
        for (int kk2 = 2; kk2 <= 64; kk2 <<= 1) {
            #pragma unroll
            for (int j = kk2 >> 1; j > 0; j >>= 1) {
                const float o = __shfl_xor(v, j, 64);
                const bool keepMin = (((lane & j) == 0) == ((lane & kk2) == 0));
                v = keepMin ? fminf(v, o) : fmaxf(v, o);
            }
        }
        const float Tq = __shfl(v, k, 64);             // all lanes (R8 lesson)
        if (lane == 0) sT[wave] = Tq;
    }
    __syncthreads();                                   // B3 (tmin dead -> s.*)

    // slack >> all fast-vs-rn rounding gaps (~1e-6)
    float Ts[QPB];
    #pragma unroll
    for (int i = 0; i < QPB; ++i)
        Ts[i] = sT[i] + 1e-2f + 1e-3f * fabsf(sT[i]);

    // pass 2: re-screen (same stream); append index only
    #pragma unroll 2
    for (int t = 0; t < EPT; ++t) {
        const int m = t * NT + tid;
        const float4 p = pq4[m];
        #pragma unroll
        for (int i = 0; i < QPB; ++i) {
            const float d = p.w - fmaf(qx[i], p.x, fmaf(qy[i], p.y, qz[i] * p.z));
            if (d <= Ts[i]) {
                const unsigned int pp = atomicAdd(&cnt[i], 1u);
                if (pp < CCAP) pool.s.cidx[i][pp] = m;
            }
        }
    }
    __syncthreads();                                   // B4 — last barrier

    // select (wave w <- query w): exact rn-op-order d2 (raw pos), u64 rank
    const int q = wave;
    const float4 qq = sq[q];
    const int cn0 = (int)cnt[q];
    const int cn = cn0 < CCAP ? cn0 : CCAP;
    for (int e = lane; e < cn; e += 64) {
        const int m = pool.s.cidx[q][e];
        const float px = posb[m * 3 + 0];
        const float py = posb[m * 3 + 1];
        const float pz = posb[m * 3 + 2];
        const float sqm = __fadd_rn(__fadd_rn(__fmul_rn(px, px), __fmul_rn(py, py)),
                                    __fmul_rn(pz, pz));
        const float dot = __fadd_rn(__fadd_rn(__fmul_rn(qq.x, px), __fmul_rn(qq.y, py)),
                                    __fmul_rn(qq.z, pz));
        const float d2 = __fsub_rn(__fadd_rn(qq.w, sqm), __fmul_rn(2.0f, dot));
        const unsigned int u = __float_as_uint(d2);
        const unsigned int kk = u ^ ((unsigned int)((int)u >> 31) | 0x80000000u);
        pool.s.pkbuf[q][e] = ((unsigned long long)kk << 12) | (unsigned int)m;
    }
    for (int e = lane; e < cn; e += 64) {
        const unsigned long long xv = pool.s.pkbuf[q][e];
        int r = 0;
        for (int j = 0; j < cn; ++j) r += (pool.s.pkbuf[q][j] < xv);
        if (r <= k) idx21[q][r] = (int)(xv & 0xFFFu);
    }
    // wave-private LDS RAW: in-order per wave + compiler lgkmcnt, no barrier

    // phase B (wave-private): scores, softmax, Wh-row gather
    const int row = qbase + q;
    const bool valid = (lane >= 1 && lane <= k);
    const int nbr = valid ? idx21[q][lane] : 0;
    const float f1v = f1[row];
    float e = -FLT_MAX;
    if (valid) {
        e = f1v + f2[(b << 12) + nbr];
        e = e > 0.f ? e : LRELU_ALPHA * e;
    }
    float mx = e;
    #pragma unroll
    for (int off = 32; off > 0; off >>= 1) mx = fmaxf(mx, __shfl_xor(mx, off, 64));
    const float ex = valid ? __expf(e - mx) : 0.f;
    float Z = ex;
    #pragma unroll
    for (int off = 32; off > 0; off >>= 1) Z += __shfl_xor(Z, off, 64);
    const float attn = ex / Z;                         // lane t holds attn_t

    const float* whb = Wh + (((size_t)b << 12) << 6);
    float h = 0.f;
    #pragma unroll 4
    for (int t = 1; t <= k; ++t) {
        const int nb_ = __shfl(nbr, t, 64);
        const float s = __shfl(attn, t, 64);
        h = fmaf(s, whb[((size_t)nb_ << 6) + lane], h);
    }

    const float pv = fmaf(qq.x, Wp[0 * FD + lane],
                     fmaf(qq.y, Wp[1 * FD + lane],
                     fmaf(qq.z, Wp[2 * FD + lane], bp[lane])));
    h += pv > 0.f ? pv : 0.f;
    out[((size_t)row << 6) + lane] = h > 0.f ? h : expm1f(h);
}

extern "C" void kernel_launch(void* const* d_in, const int* in_sizes, int n_in,
                              void* d_out, int out_size, void* d_ws, size_t ws_size,
                              hipStream_t stream) {
    const float* x   = (const float*)d_in[0];
    const float* pos = (const float*)d_in[1];
    const float* W   = (const float*)d_in[2];
    const float* a   = (const float*)d_in[3];
    const float* Wp  = (const float*)d_in[4];
    const float* bp  = (const float*)d_in[5];
    const int*   kp  = (const int*)d_in[6];

    float* ws = (float*)d_ws;
    float*  Wh = ws;                        // 8192*64 = 524288
    float*  f1 = Wh + 524288;               // 8192
    float*  f2 = f1 + 8192;                 // 8192
    float4* pq = (float4*)(f2 + 8192);      // 8192 float4 (16B-aligned)
    float*  out = (float*)d_out;

    prep_kernel<<<544, 256, 0, stream>>>(x, pos, W, a, Wh, f1, f2, pq);
    gat_fused<<<(NB * 2) / QPB, NT, 0, stream>>>(pos, pq, Wh, f1, f2, Wp, bp, kp, out);
}